// Round 6
// baseline (72791.010 us; speedup 1.0000x reference)
//
#include <hip/hip_runtime.h>

#define TT 4096
#define DD 2048  // IN == HID == OUT
#define NBLK 128
#define FLAG_STRIDE 32  // ints; 128 B between flags

// ---------------------------------------------------------------------------
// C[M][N] = A[M][K] @ B[N][K]^T + bias[N]   (fp32, all dims multiples of 128)
// 128x128 tile, K-step 32, 256 threads, 8x8 accumulators per thread.
// ---------------------------------------------------------------------------
__global__ __launch_bounds__(256)
void gemm_nt_bias(float* __restrict__ C, const float* __restrict__ A,
                  const float* __restrict__ B, const float* __restrict__ bias,
                  int M, int N, int K)
{
    __shared__ float As[32][132];  // [k][m], +4 pad
    __shared__ float Bs[32][132];  // [k][n], +4 pad

    const int tid = threadIdx.x;
    const int m0 = blockIdx.y * 128;
    const int n0 = blockIdx.x * 128;
    const int tn = tid & 15;   // fastest -> coalesced C stores
    const int tm = tid >> 4;

    float acc[8][8];
#pragma unroll
    for (int i = 0; i < 8; ++i)
#pragma unroll
        for (int j = 0; j < 8; ++j) acc[i][j] = 0.f;

    float bfr[8];
#pragma unroll
    for (int j = 0; j < 8; ++j) bfr[j] = bias[n0 + tn * 8 + j];

    const int lr = tid >> 3;        // 0..31
    const int lc = (tid & 7) * 4;   // 0,4,...,28

    for (int kt = 0; kt < K; kt += 32) {
#pragma unroll
        for (int i = 0; i < 4; ++i) {
            const int r = lr + i * 32;
            const float4 av = *(const float4*)&A[(size_t)(m0 + r) * K + kt + lc];
            As[lc + 0][r] = av.x; As[lc + 1][r] = av.y;
            As[lc + 2][r] = av.z; As[lc + 3][r] = av.w;
            const float4 bv = *(const float4*)&B[(size_t)(n0 + r) * K + kt + lc];
            Bs[lc + 0][r] = bv.x; Bs[lc + 1][r] = bv.y;
            Bs[lc + 2][r] = bv.z; Bs[lc + 3][r] = bv.w;
        }
        __syncthreads();
#pragma unroll 8
        for (int kk = 0; kk < 32; ++kk) {
            float a[8], b[8];
            *(float4*)&a[0] = *(const float4*)&As[kk][tm * 8];
            *(float4*)&a[4] = *(const float4*)&As[kk][tm * 8 + 4];
            *(float4*)&b[0] = *(const float4*)&Bs[kk][tn * 8];
            *(float4*)&b[4] = *(const float4*)&Bs[kk][tn * 8 + 4];
#pragma unroll
            for (int i = 0; i < 8; ++i)
#pragma unroll
                for (int j = 0; j < 8; ++j)
                    acc[i][j] = fmaf(a[i], b[j], acc[i][j]);
        }
        __syncthreads();
    }

#pragma unroll
    for (int i = 0; i < 8; ++i) {
        float* cp = &C[(size_t)(m0 + tm * 8 + i) * N + n0 + tn * 8];
        const float4 o0 = make_float4(acc[i][0] + bfr[0], acc[i][1] + bfr[1],
                                      acc[i][2] + bfr[2], acc[i][3] + bfr[3]);
        const float4 o1 = make_float4(acc[i][4] + bfr[4], acc[i][5] + bfr[5],
                                      acc[i][6] + bfr[6], acc[i][7] + bfr[7]);
        *(float4*)cp = o0;
        *(float4*)(cp + 4) = o1;
    }
}

// ---------------------------------------------------------------------------
// Persistent recurrence, one-sided dataflow sync (no grid barrier).
// 128 blocks x 512 threads; block b owns rows [16b,16b+16) of W_hh in LDS.
// XH [TT][DD]: x_proj on entry, row t overwritten in place with h_t.
// Protocol: block b after step t: agent-stores h rows -> release fence ->
// flag[b]=t+1. Reader at step t polls all flags >= t, acquire fence, then
// agent-loads h_{t-1}. No WAR hazard (fresh row per t) => no second phase.
// Skew bound: computing step t implies all blocks completed t-1 (skew <= 1).
// Cooperative launch used ONLY as a co-residency guarantee.
// ---------------------------------------------------------------------------
__global__ __launch_bounds__(512)
void rnn_seq(float* __restrict__ XH, const float* __restrict__ h_prev,
             const float* __restrict__ W_hh, const float* __restrict__ b_hh,
             float* __restrict__ h_final, int* __restrict__ flags)
{
    extern __shared__ float smem[];
    float* wsm = smem;            // [16][2048]
    float* hsm = smem + 16 * DD;  // [2048]

    const int tid  = threadIdx.x;
    const int lane = tid & 63;
    const int wave = tid >> 6;          // 0..7, each wave owns 2 rows
    const int r0   = blockIdx.x * 16;

    // stage this block's 16 W_hh rows into LDS (once)
    for (int i = tid; i < 16 * (DD / 4); i += 512) {
        const int row = i / (DD / 4);
        const int c4  = (i % (DD / 4)) * 4;
        *(float4*)&wsm[row * DD + c4] =
            *(const float4*)&W_hh[(size_t)(r0 + row) * DD + c4];
    }
    __syncthreads();

    const int myrow = wave * 2 + (lane & 1);
    const float bh = b_hh[r0 + myrow];

    for (int t = 0; t < TT; ++t) {
        // x_proj for my row (plain load: written by gemm1, then only by me)
        const float xp = XH[(size_t)t * DD + r0 + myrow];

        if (t == 0) {
            const int i4 = tid * 4;  // 512 threads x float4 = 2048
            *(float4*)&hsm[i4] = *(const float4*)&h_prev[i4];
        } else {
            // wait for every block to have published step t-1
            if (tid < NBLK) {
                while (__hip_atomic_load(&flags[tid * FLAG_STRIDE],
                                         __ATOMIC_RELAXED,
                                         __HIP_MEMORY_SCOPE_AGENT) < t) {
                    __builtin_amdgcn_s_sleep(1);
                }
            }
            __syncthreads();
            __builtin_amdgcn_fence(__ATOMIC_ACQUIRE, "agent");
            // stage h_{t-1}: 8B agent loads (bypass non-coherent L2)
            const unsigned long long* hp64 =
                (const unsigned long long*)&XH[(size_t)(t - 1) * DD];
            unsigned long long v0 = __hip_atomic_load(&hp64[tid], __ATOMIC_RELAXED,
                                                      __HIP_MEMORY_SCOPE_AGENT);
            unsigned long long v1 = __hip_atomic_load(&hp64[tid + 512], __ATOMIC_RELAXED,
                                                      __HIP_MEMORY_SCOPE_AGENT);
            ((unsigned long long*)hsm)[tid]       = v0;
            ((unsigned long long*)hsm)[tid + 512] = v1;
        }
        __syncthreads();

        // each wave: 2 rows, full-wave contiguous sweep (conflict-free)
        float acc0 = 0.f, acc1 = 0.f;
        const float* w0p = &wsm[(wave * 2 + 0) * DD];
        const float* w1p = &wsm[(wave * 2 + 1) * DD];
#pragma unroll
        for (int win = 0; win < 8; ++win) {
            const int base = win * 256 + lane * 4;
            const float4 hv = *(const float4*)&hsm[base];
            const float4 w0 = *(const float4*)&w0p[base];
            const float4 w1 = *(const float4*)&w1p[base];
            acc0 = fmaf(w0.x, hv.x, acc0); acc0 = fmaf(w0.y, hv.y, acc0);
            acc0 = fmaf(w0.z, hv.z, acc0); acc0 = fmaf(w0.w, hv.w, acc0);
            acc1 = fmaf(w1.x, hv.x, acc1); acc1 = fmaf(w1.y, hv.y, acc1);
            acc1 = fmaf(w1.z, hv.z, acc1); acc1 = fmaf(w1.w, hv.w, acc1);
        }
#pragma unroll
        for (int m = 1; m < 64; m <<= 1) {
            acc0 += __shfl_xor(acc0, m);
            acc1 += __shfl_xor(acc1, m);
        }

        if (lane < 2) {  // lane 0 -> row wave*2, lane 1 -> row wave*2+1
            const float s = (lane == 0) ? acc0 : acc1;
            const float v = s + bh + xp;
            const float hn = 1.f - 2.f / (__expf(2.f * v) + 1.f);  // tanh(v)
            __hip_atomic_store(&XH[(size_t)t * DD + r0 + myrow], hn,
                               __ATOMIC_RELAXED, __HIP_MEMORY_SCOPE_AGENT);
            if (t == TT - 1) h_final[r0 + myrow] = hn;
        }
        // publish: all h-stores agent-visible, then advance my flag
        __builtin_amdgcn_fence(__ATOMIC_RELEASE, "agent");
        __syncthreads();
        if (tid == 0)
            __hip_atomic_store(&flags[blockIdx.x * FLAG_STRIDE], t + 1,
                               __ATOMIC_RELAXED, __HIP_MEMORY_SCOPE_AGENT);
    }
}

// ---------------------------------------------------------------------------
extern "C" void kernel_launch(void* const* d_in, const int* in_sizes, int n_in,
                              void* d_out, int out_size, void* d_ws, size_t ws_size,
                              hipStream_t stream)
{
    (void)in_sizes; (void)n_in; (void)out_size; (void)ws_size;
    const float* x_seq  = (const float*)d_in[0];
    const float* h_prev = (const float*)d_in[1];
    const float* W_ih   = (const float*)d_in[2];
    const float* b_ih   = (const float*)d_in[3];
    const float* W_hh   = (const float*)d_in[4];
    const float* b_hh   = (const float*)d_in[5];
    const float* W_fc   = (const float*)d_in[6];
    const float* b_fc   = (const float*)d_in[7];
    float* out = (float*)d_out;
    float* XH  = (float*)d_ws;                       // [TT][DD], 33.5 MB
    int*   flags = (int*)((char*)d_ws + (size_t)TT * DD * sizeof(float));
    float* h_final = out + (size_t)TT * DD;

    // flags poisoned 0xAA by harness -> zero them (async, capture-safe)
    (void)hipMemsetAsync(flags, 0, NBLK * FLAG_STRIDE * sizeof(int), stream);

    dim3 gg(DD / 128, TT / 128);
    // 1) x_proj = x_seq @ W_ih^T + b_ih
    gemm_nt_bias<<<gg, dim3(256), 0, stream>>>(XH, x_seq, W_ih, b_ih, TT, DD, DD);

    // 2) sequential scan (persistent, dataflow-synced)
    const int smem = (16 * DD + DD) * (int)sizeof(float);  // 139,264 B
    (void)hipFuncSetAttribute((const void*)rnn_seq,
                              hipFuncAttributeMaxDynamicSharedMemorySize, smem);
    void* args[6];
    args[0] = (void*)&XH;
    args[1] = (void*)&h_prev;
    args[2] = (void*)&W_hh;
    args[3] = (void*)&b_hh;
    args[4] = (void*)&h_final;
    args[5] = (void*)&flags;
    (void)hipLaunchCooperativeKernel((void*)rnn_seq, dim3(NBLK), dim3(512),
                                     args, (unsigned)smem, stream);

    // 3) logits = H @ W_fc^T + b_fc
    gemm_nt_bias<<<gg, dim3(256), 0, stream>>>(out, XH, W_fc, b_fc, TT, DD, DD);
}

// Round 12
// 14924.503 us; speedup vs baseline: 4.8773x; 4.8773x over previous
//
#include <hip/hip_runtime.h>

#define TT 4096
#define DD 2048  // IN == HID == OUT
#define NBLK 128
#define FLAG_STRIDE 32  // ints; 128 B between flags

// ---------------------------------------------------------------------------
// C[M][N] = A[M][K] @ B[N][K]^T + bias[N]   (fp32, all dims multiples of 128)
// 128x128 tile, K-step 32, 256 threads, 8x8 accumulators per thread.
// ---------------------------------------------------------------------------
__global__ __launch_bounds__(256)
void gemm_nt_bias(float* __restrict__ C, const float* __restrict__ A,
                  const float* __restrict__ B, const float* __restrict__ bias,
                  int M, int N, int K)
{
    __shared__ float As[32][132];  // [k][m], +4 pad
    __shared__ float Bs[32][132];  // [k][n], +4 pad

    const int tid = threadIdx.x;
    const int m0 = blockIdx.y * 128;
    const int n0 = blockIdx.x * 128;
    const int tn = tid & 15;   // fastest -> coalesced C stores
    const int tm = tid >> 4;

    float acc[8][8];
#pragma unroll
    for (int i = 0; i < 8; ++i)
#pragma unroll
        for (int j = 0; j < 8; ++j) acc[i][j] = 0.f;

    float bfr[8];
#pragma unroll
    for (int j = 0; j < 8; ++j) bfr[j] = bias[n0 + tn * 8 + j];

    const int lr = tid >> 3;        // 0..31
    const int lc = (tid & 7) * 4;   // 0,4,...,28

    for (int kt = 0; kt < K; kt += 32) {
#pragma unroll
        for (int i = 0; i < 4; ++i) {
            const int r = lr + i * 32;
            const float4 av = *(const float4*)&A[(size_t)(m0 + r) * K + kt + lc];
            As[lc + 0][r] = av.x; As[lc + 1][r] = av.y;
            As[lc + 2][r] = av.z; As[lc + 3][r] = av.w;
            const float4 bv = *(const float4*)&B[(size_t)(n0 + r) * K + kt + lc];
            Bs[lc + 0][r] = bv.x; Bs[lc + 1][r] = bv.y;
            Bs[lc + 2][r] = bv.z; Bs[lc + 3][r] = bv.w;
        }
        __syncthreads();
#pragma unroll 8
        for (int kk = 0; kk < 32; ++kk) {
            float a[8], b[8];
            *(float4*)&a[0] = *(const float4*)&As[kk][tm * 8];
            *(float4*)&a[4] = *(const float4*)&As[kk][tm * 8 + 4];
            *(float4*)&b[0] = *(const float4*)&Bs[kk][tn * 8];
            *(float4*)&b[4] = *(const float4*)&Bs[kk][tn * 8 + 4];
#pragma unroll
            for (int i = 0; i < 8; ++i)
#pragma unroll
                for (int j = 0; j < 8; ++j)
                    acc[i][j] = fmaf(a[i], b[j], acc[i][j]);
        }
        __syncthreads();
    }

#pragma unroll
    for (int i = 0; i < 8; ++i) {
        float* cp = &C[(size_t)(m0 + tm * 8 + i) * N + n0 + tn * 8];
        const float4 o0 = make_float4(acc[i][0] + bfr[0], acc[i][1] + bfr[1],
                                      acc[i][2] + bfr[2], acc[i][3] + bfr[3]);
        const float4 o1 = make_float4(acc[i][4] + bfr[4], acc[i][5] + bfr[5],
                                      acc[i][6] + bfr[6], acc[i][7] + bfr[7]);
        *(float4*)cp = o0;
        *(float4*)(cp + 4) = o1;
    }
}

// ---------------------------------------------------------------------------
// SHADOW-BENCH variant (writes to d_ws scratch only; NOT used for d_out).
// Same math/tiling, but double-buffered LDS with register prefetch of the
// next K-tile during compute -> one barrier per K-step, HBM latency hidden.
// Dynamic LDS: 2 * (4224 + 4224) floats = 67584 B.
// ---------------------------------------------------------------------------
__global__ __launch_bounds__(256)
void gemm_nt_bias_dbuf(float* __restrict__ C, const float* __restrict__ A,
                       const float* __restrict__ B, const float* __restrict__ bias,
                       int M, int N, int K)
{
    extern __shared__ float sm[];  // [2][ As 32x132 | Bs 32x132 ]
    const int tid = threadIdx.x;
    const int m0 = blockIdx.y * 128;
    const int n0 = blockIdx.x * 128;
    const int tn = tid & 15;
    const int tm = tid >> 4;
    const int lr = tid >> 3;
    const int lc = (tid & 7) * 4;

    float acc[8][8];
#pragma unroll
    for (int i = 0; i < 8; ++i)
#pragma unroll
        for (int j = 0; j < 8; ++j) acc[i][j] = 0.f;

    float bfr[8];
#pragma unroll
    for (int j = 0; j < 8; ++j) bfr[j] = bias[n0 + tn * 8 + j];

    float4 av[4], bv[4];
    // prologue: load + stage K-tile 0 into buffer 0
#pragma unroll
    for (int i = 0; i < 4; ++i) {
        const int r = lr + i * 32;
        av[i] = *(const float4*)&A[(size_t)(m0 + r) * K + lc];
        bv[i] = *(const float4*)&B[(size_t)(n0 + r) * K + lc];
    }
    {
        float* As0 = sm;
        float* Bs0 = sm + 4224;
#pragma unroll
        for (int i = 0; i < 4; ++i) {
            const int r = lr + i * 32;
            As0[(lc + 0) * 132 + r] = av[i].x; As0[(lc + 1) * 132 + r] = av[i].y;
            As0[(lc + 2) * 132 + r] = av[i].z; As0[(lc + 3) * 132 + r] = av[i].w;
            Bs0[(lc + 0) * 132 + r] = bv[i].x; Bs0[(lc + 1) * 132 + r] = bv[i].y;
            Bs0[(lc + 2) * 132 + r] = bv[i].z; Bs0[(lc + 3) * 132 + r] = bv[i].w;
        }
    }
    __syncthreads();

    for (int kt = 0; kt < K; kt += 32) {
        const int cur = (kt >> 5) & 1;
        const float* Asc = sm + cur * 8448;
        const float* Bsc = sm + cur * 8448 + 4224;
        const bool more = (kt + 32) < K;
        if (more) {  // issue next-tile loads; in flight during compute below
#pragma unroll
            for (int i = 0; i < 4; ++i) {
                const int r = lr + i * 32;
                av[i] = *(const float4*)&A[(size_t)(m0 + r) * K + kt + 32 + lc];
                bv[i] = *(const float4*)&B[(size_t)(n0 + r) * K + kt + 32 + lc];
            }
        }
#pragma unroll 8
        for (int kk = 0; kk < 32; ++kk) {
            float a[8], b[8];
            *(float4*)&a[0] = *(const float4*)&Asc[kk * 132 + tm * 8];
            *(float4*)&a[4] = *(const float4*)&Asc[kk * 132 + tm * 8 + 4];
            *(float4*)&b[0] = *(const float4*)&Bsc[kk * 132 + tn * 8];
            *(float4*)&b[4] = *(const float4*)&Bsc[kk * 132 + tn * 8 + 4];
#pragma unroll
            for (int i = 0; i < 8; ++i)
#pragma unroll
                for (int j = 0; j < 8; ++j)
                    acc[i][j] = fmaf(a[i], b[j], acc[i][j]);
        }
        if (more) {  // write next tile to the other buffer (no reader conflict)
            float* Asn = sm + (cur ^ 1) * 8448;
            float* Bsn = sm + (cur ^ 1) * 8448 + 4224;
#pragma unroll
            for (int i = 0; i < 4; ++i) {
                const int r = lr + i * 32;
                Asn[(lc + 0) * 132 + r] = av[i].x; Asn[(lc + 1) * 132 + r] = av[i].y;
                Asn[(lc + 2) * 132 + r] = av[i].z; Asn[(lc + 3) * 132 + r] = av[i].w;
                Bsn[(lc + 0) * 132 + r] = bv[i].x; Bsn[(lc + 1) * 132 + r] = bv[i].y;
                Bsn[(lc + 2) * 132 + r] = bv[i].z; Bsn[(lc + 3) * 132 + r] = bv[i].w;
            }
        }
        __syncthreads();  // one barrier per K-step
    }

#pragma unroll
    for (int i = 0; i < 8; ++i) {
        float* cp = &C[(size_t)(m0 + tm * 8 + i) * N + n0 + tn * 8];
        const float4 o0 = make_float4(acc[i][0] + bfr[0], acc[i][1] + bfr[1],
                                      acc[i][2] + bfr[2], acc[i][3] + bfr[3]);
        const float4 o1 = make_float4(acc[i][4] + bfr[4], acc[i][5] + bfr[5],
                                      acc[i][6] + bfr[6], acc[i][7] + bfr[7]);
        *(float4*)cp = o0;
        *(float4*)(cp + 4) = o1;
    }
}

// ---------------------------------------------------------------------------
// Persistent recurrence, one-sided dataflow sync, FENCELESS.
// All cross-block traffic (flags, h) uses agent-scope relaxed atomics, which
// are serviced at the agent coherence point (bypassing non-coherent per-XCD
// caches) -> no acquire/release FENCES needed. Ordering:
//   producer: h agent-stores -> __syncthreads (per-thread vmcnt(0) drain =>
//             h agent-visible) -> RELEASE flag store by tid 0.
//   consumer: poll flag (control dep) -> agent h-loads (in-order issue).
// The r6 profile showed 16.6us/step with per-step agent fences (suspected
// buffer_inv cache shoot-downs); this round removes them.
// ---------------------------------------------------------------------------
__global__ __launch_bounds__(512)
void rnn_seq(float* __restrict__ XH, const float* __restrict__ h_prev,
             const float* __restrict__ W_hh, const float* __restrict__ b_hh,
             float* __restrict__ h_final, int* __restrict__ flags)
{
    extern __shared__ float smem[];
    float* wsm = smem;            // [16][2048]
    float* hsm = smem + 16 * DD;  // [2048]

    const int tid  = threadIdx.x;
    const int lane = tid & 63;
    const int wave = tid >> 6;          // 0..7, each wave owns 2 rows
    const int r0   = blockIdx.x * 16;

    // stage this block's 16 W_hh rows into LDS (once)
    for (int i = tid; i < 16 * (DD / 4); i += 512) {
        const int row = i / (DD / 4);
        const int c4  = (i % (DD / 4)) * 4;
        *(float4*)&wsm[row * DD + c4] =
            *(const float4*)&W_hh[(size_t)(r0 + row) * DD + c4];
    }
    __syncthreads();

    const int myrow = wave * 2 + (lane & 1);
    const float bh = b_hh[r0 + myrow];

    for (int t = 0; t < TT; ++t) {
        // x_proj for my row (plain load: written by gemm1, then only by me)
        const float xp = XH[(size_t)t * DD + r0 + myrow];

        if (t == 0) {
            const int i4 = tid * 4;  // 512 threads x float4 = 2048
            *(float4*)&hsm[i4] = *(const float4*)&h_prev[i4];
        } else {
            // wait for every block to have published step t-1 (no sleep:
            // poll period is naturally >= the atomic-load latency)
            if (tid < NBLK) {
                while (__hip_atomic_load(&flags[tid * FLAG_STRIDE],
                                         __ATOMIC_RELAXED,
                                         __HIP_MEMORY_SCOPE_AGENT) < t) {}
            }
            __syncthreads();
            // stage h_{t-1}: 8B agent loads (serviced at coherence point)
            const unsigned long long* hp64 =
                (const unsigned long long*)&XH[(size_t)(t - 1) * DD];
            unsigned long long v0 = __hip_atomic_load(&hp64[tid], __ATOMIC_RELAXED,
                                                      __HIP_MEMORY_SCOPE_AGENT);
            unsigned long long v1 = __hip_atomic_load(&hp64[tid + 512], __ATOMIC_RELAXED,
                                                      __HIP_MEMORY_SCOPE_AGENT);
            ((unsigned long long*)hsm)[tid]       = v0;
            ((unsigned long long*)hsm)[tid + 512] = v1;
        }
        __syncthreads();

        // each wave: 2 rows, full-wave contiguous sweep (conflict-free)
        float acc0 = 0.f, acc1 = 0.f;
        const float* w0p = &wsm[(wave * 2 + 0) * DD];
        const float* w1p = &wsm[(wave * 2 + 1) * DD];
#pragma unroll
        for (int win = 0; win < 8; ++win) {
            const int base = win * 256 + lane * 4;
            const float4 hv = *(const float4*)&hsm[base];
            const float4 w0 = *(const float4*)&w0p[base];
            const float4 w1 = *(const float4*)&w1p[base];
            acc0 = fmaf(w0.x, hv.x, acc0); acc0 = fmaf(w0.y, hv.y, acc0);
            acc0 = fmaf(w0.z, hv.z, acc0); acc0 = fmaf(w0.w, hv.w, acc0);
            acc1 = fmaf(w1.x, hv.x, acc1); acc1 = fmaf(w1.y, hv.y, acc1);
            acc1 = fmaf(w1.z, hv.z, acc1); acc1 = fmaf(w1.w, hv.w, acc1);
        }
#pragma unroll
        for (int m = 1; m < 64; m <<= 1) {
            acc0 += __shfl_xor(acc0, m);
            acc1 += __shfl_xor(acc1, m);
        }

        if (lane < 2) {  // lane 0 -> row wave*2, lane 1 -> row wave*2+1
            const float s = (lane == 0) ? acc0 : acc1;
            const float v = s + bh + xp;
            const float hn = 1.f - 2.f / (__expf(2.f * v) + 1.f);  // tanh(v)
            __hip_atomic_store(&XH[(size_t)t * DD + r0 + myrow], hn,
                               __ATOMIC_RELAXED, __HIP_MEMORY_SCOPE_AGENT);
            if (t == TT - 1) h_final[r0 + myrow] = hn;
        }
        // __syncthreads drains every thread's vmcnt -> all h agent-stores
        // are agent-visible; then tid 0 publishes with a release store.
        __syncthreads();
        if (tid == 0)
            __hip_atomic_store(&flags[blockIdx.x * FLAG_STRIDE], t + 1,
                               __ATOMIC_RELEASE, __HIP_MEMORY_SCOPE_AGENT);
    }
}

// ---------------------------------------------------------------------------
extern "C" void kernel_launch(void* const* d_in, const int* in_sizes, int n_in,
                              void* d_out, int out_size, void* d_ws, size_t ws_size,
                              hipStream_t stream)
{
    (void)in_sizes; (void)n_in; (void)out_size;
    const float* x_seq  = (const float*)d_in[0];
    const float* h_prev = (const float*)d_in[1];
    const float* W_ih   = (const float*)d_in[2];
    const float* b_ih   = (const float*)d_in[3];
    const float* W_hh   = (const float*)d_in[4];
    const float* b_hh   = (const float*)d_in[5];
    const float* W_fc   = (const float*)d_in[6];
    const float* b_fc   = (const float*)d_in[7];
    float* out = (float*)d_out;
    float* XH  = (float*)d_ws;                       // [TT][DD], 33.5 MB
    int*   flags = (int*)((char*)d_ws + (size_t)TT * DD * sizeof(float));
    float* h_final = out + (size_t)TT * DD;

    // flags poisoned 0xAA by harness -> zero them (async, capture-safe)
    (void)hipMemsetAsync(flags, 0, NBLK * FLAG_STRIDE * sizeof(int), stream);

    dim3 gg(DD / 128, TT / 128);
    // 1) x_proj = x_seq @ W_ih^T + b_ih
    gemm_nt_bias<<<gg, dim3(256), 0, stream>>>(XH, x_seq, W_ih, b_ih, TT, DD, DD);

    // 2) sequential scan (persistent, dataflow-synced)
    const int smem = (16 * DD + DD) * (int)sizeof(float);  // 139,264 B
    (void)hipFuncSetAttribute((const void*)rnn_seq,
                              hipFuncAttributeMaxDynamicSharedMemorySize, smem);
    void* args[6];
    args[0] = (void*)&XH;
    args[1] = (void*)&h_prev;
    args[2] = (void*)&W_hh;
    args[3] = (void*)&b_hh;
    args[4] = (void*)&h_final;
    args[5] = (void*)&flags;
    (void)hipLaunchCooperativeKernel((void*)rnn_seq, dim3(NBLK), dim3(512),
                                     args, (unsigned)smem, stream);

    // 3) logits = H @ W_fc^T + b_fc
    gemm_nt_bias<<<gg, dim3(256), 0, stream>>>(out, XH, W_fc, b_fc, TT, DD, DD);

    // 4) SHADOW BENCH (scratch-only, zero correctness risk): double-buffered
    //    GEMM variant on the x_proj shapes; timing read from rocprof/dur_us.
    const size_t shadow_off = (size_t)TT * DD * sizeof(float)
                            + (size_t)NBLK * FLAG_STRIDE * sizeof(int);
    const size_t shadow_bytes = (size_t)TT * DD * sizeof(float);
    if (ws_size >= shadow_off + shadow_bytes) {
        float* Cs = (float*)((char*)d_ws + shadow_off);
        (void)hipFuncSetAttribute((const void*)gemm_nt_bias_dbuf,
                                  hipFuncAttributeMaxDynamicSharedMemorySize, 67584);
        gemm_nt_bias_dbuf<<<gg, dim3(256), 67584, stream>>>(Cs, x_seq, W_ih, b_ih,
                                                            TT, DD, DD);
    }
}